// Round 4
// baseline (549.647 us; speedup 1.0000x reference)
//
#include <hip/hip_runtime.h>
#include <math.h>

namespace {

constexpr int Bb = 4, Ss = 256, Dd = 768, Vv = 50257;
constexpr int Mm = Bb * Ss;               // 1024 rows
constexpr int BM = 128, BN = 128, BK = 32;
constexpr int NS = Dd / BK;               // 24 k-steps
constexpr int TW = (Vv + BN - 1) / BN;    // 393 W tiles (last padded w/ zeros)
constexpr int TA = Mm / BM;               // 8 A tiles
constexpr int CHUNK = BM * BK;            // 4096 f16 = 8 KB per (tile, step) per plane
constexpr float SC = 14.4269504088896341f;   // 10 * log2(e)

typedef _Float16 f16x8 __attribute__((ext_vector_type(8)));
typedef float f32x4 __attribute__((ext_vector_type(4)));

// Packed scratch layout (inside out3 region, overwritten by finalize at the end):
//   Whp[TW*NS*CHUNK] , Wlp[...] , Ahp[TA*NS*CHUNK] , Alp[...] , tsq[Vv] (f32)
constexpr size_t WPLANE = (size_t)TW * NS * CHUNK;   // 38,633,472 f16
constexpr size_t APLANE = (size_t)TA * NS * CHUNK;   //    786,432 f16
// total bytes = 2*(WPLANE+APLANE)*2 + Vv*4 = 157,880,644 < out3 bytes (205,852,672)

__device__ __forceinline__ void gload_lds16(const void* g, void* l) {
    typedef __attribute__((address_space(3))) void lds_t;
    typedef const __attribute__((address_space(1))) void gm_t;
    __builtin_amdgcn_global_load_lds((gm_t*)g, (lds_t*)l, 16, 0, 0);
}

// ---------------------------------------------------------------------------
// Kernel 1: t_sq[v] = sum_d W[v][d]^2   (one wave per vocab row)
// ---------------------------------------------------------------------------
__global__ __launch_bounds__(256) void tsq_kernel(const float* __restrict__ W,
                                                  float* __restrict__ tsq) {
    int gid  = blockIdx.x * blockDim.x + threadIdx.x;
    int wave = gid >> 6;
    int lane = threadIdx.x & 63;
    if (wave >= Vv) return;
    const float4* row = reinterpret_cast<const float4*>(W + (size_t)wave * Dd);
    float s = 0.f;
#pragma unroll
    for (int i = 0; i < 3; ++i) {
        float4 v = row[lane + 64 * i];
        s = fmaf(v.x, v.x, s);
        s = fmaf(v.y, v.y, s);
        s = fmaf(v.z, v.z, s);
        s = fmaf(v.w, v.w, s);
    }
#pragma unroll
    for (int off = 32; off > 0; off >>= 1) s += __shfl_down(s, off);
    if (lane == 0) tsq[wave] = s;
}

// ---------------------------------------------------------------------------
// Kernel 1b: split fp32 -> (hi,lo) f16 planes, packed in GEMM tile order.
// Chunk layout for (tile t, step s): elem (fq, r, e) at  chunk + fq*(BM*8) + r*8 + e
//   == exactly the linear order global_load_lds writes LDS (lane r -> 16B).
// grid = (ntiles, 12), block 256 = 4 waves; wave handles one (s, half) unit.
// Rows >= nrows are written as ZEROS (kills bounds checks in GEMM).
// ---------------------------------------------------------------------------
__global__ __launch_bounds__(256) void convert_pack(const float* __restrict__ src,
                                                    _Float16* __restrict__ hp,
                                                    _Float16* __restrict__ lp,
                                                    int nrows) {
    const int t    = blockIdx.x;
    const int wid  = threadIdx.x >> 6;
    const int lane = threadIdx.x & 63;
    const int u    = blockIdx.y * 4 + wid;    // 0..47
    const int s    = u >> 1;
    const int half = u & 1;
    const int r    = half * 64 + lane;
    const int v    = t * BM + r;

    float vals[32];
    if (v < nrows) {
        const float4* p = reinterpret_cast<const float4*>(src + (size_t)v * Dd + s * BK);
#pragma unroll
        for (int i = 0; i < 8; ++i) *reinterpret_cast<float4*>(&vals[4 * i]) = p[i];
    } else {
#pragma unroll
        for (int i = 0; i < 32; ++i) vals[i] = 0.f;
    }
    const size_t chunk = ((size_t)t * NS + s) * CHUNK;
#pragma unroll
    for (int fq = 0; fq < 4; ++fq) {
        _Float16 hi[8], lo[8];
#pragma unroll
        for (int e = 0; e < 8; ++e) {
            const float x = vals[fq * 8 + e];
            const _Float16 h = (_Float16)x;
            hi[e] = h;
            lo[e] = (_Float16)(x - (float)h);
        }
        *reinterpret_cast<f16x8*>(&hp[chunk + fq * (BM * 8) + (size_t)r * 8]) =
            *reinterpret_cast<const f16x8*>(hi);
        *reinterpret_cast<f16x8*>(&lp[chunk + fq * (BM * 8) + (size_t)r * 8]) =
            *reinterpret_cast<const f16x8*>(lo);
    }
}

// ---------------------------------------------------------------------------
// Kernel 2: scores = 2*(A.W^T) - tsq  via packed split-f16 MFMA, m97 structure:
// global_load_lds staging, conflict-free k-major LDS, 128x128x32, 4 waves.
// ---------------------------------------------------------------------------
__global__ __launch_bounds__(256) void gemm_kernel(const _Float16* __restrict__ Ahp,
                                                   const _Float16* __restrict__ Alp,
                                                   const _Float16* __restrict__ Whp,
                                                   const _Float16* __restrict__ Wlp,
                                                   const float* __restrict__ tsq,
                                                   float* __restrict__ scores) {
    __shared__ _Float16 lds[4][CHUNK];     // 0:Ah 1:Al 2:Wh 3:Wl  (32 KB)

    const int tid  = threadIdx.x;
    const int wid  = tid >> 6;
    const int lane = tid & 63;
    const int wr   = wid >> 1;             // wave row (0..1)
    const int wc   = wid & 1;              // wave col (0..1)
    const int fr   = lane & 15;
    const int fq   = lane >> 4;
    const int tn   = blockIdx.x;           // W tile
    const int tm   = blockIdx.y;           // A tile

    const _Float16* gA_h = Ahp + (size_t)tm * NS * CHUNK;
    const _Float16* gA_l = Alp + (size_t)tm * NS * CHUNK;
    const _Float16* gW_h = Whp + (size_t)tn * NS * CHUNK;
    const _Float16* gW_l = Wlp + (size_t)tn * NS * CHUNK;

    f32x4 acc[4][4];
#pragma unroll
    for (int m = 0; m < 4; ++m)
#pragma unroll
        for (int n = 0; n < 4; ++n) acc[m][n] = (f32x4){0.f, 0.f, 0.f, 0.f};

    for (int s = 0; s < NS; ++s) {
        if (s) __syncthreads();            // compute of s-1 done -> LDS reusable
        const size_t so = (size_t)s * CHUNK;
        const _Float16* gsrc[4] = {gA_h + so, gA_l + so, gW_h + so, gW_l + so};
#pragma unroll
        for (int c = 0; c < 4; ++c) {
#pragma unroll
            for (int i = 0; i < 2; ++i) {
                const int seg = wid * 2 + i;              // 0..7, wave-uniform
                gload_lds16(gsrc[c] + seg * 512 + lane * 8, &lds[c][seg * 512]);
            }
        }
        __syncthreads();                   // drains vmcnt -> chunks in LDS

        f16x8 ah[4], al[4];
#pragma unroll
        for (int m = 0; m < 4; ++m) {
            const int r = wr * 64 + m * 16 + fr;
            ah[m] = *reinterpret_cast<const f16x8*>(&lds[0][fq * (BM * 8) + r * 8]);
            al[m] = *reinterpret_cast<const f16x8*>(&lds[1][fq * (BM * 8) + r * 8]);
        }
#pragma unroll
        for (int n = 0; n < 4; ++n) {
            const int c = wc * 64 + n * 16 + fr;
            const f16x8 wh = *reinterpret_cast<const f16x8*>(&lds[2][fq * (BM * 8) + c * 8]);
            const f16x8 wl = *reinterpret_cast<const f16x8*>(&lds[3][fq * (BM * 8) + c * 8]);
#pragma unroll
            for (int m = 0; m < 4; ++m) {
                acc[m][n] = __builtin_amdgcn_mfma_f32_16x16x32_f16(ah[m], wh, acc[m][n], 0, 0, 0);
                acc[m][n] = __builtin_amdgcn_mfma_f32_16x16x32_f16(al[m], wh, acc[m][n], 0, 0, 0);
                acc[m][n] = __builtin_amdgcn_mfma_f32_16x16x32_f16(ah[m], wl, acc[m][n], 0, 0, 0);
            }
        }
    }

    // epilogue: scores = 2*acc - tsq[n]   (C/D: col = lane&15, row = fq*4 + reg)
#pragma unroll
    for (int n = 0; n < 4; ++n) {
        const int gn = tn * BN + wc * 64 + n * 16 + fr;
        if (gn >= Vv) continue;
        const float t = tsq[gn];
#pragma unroll
        for (int m = 0; m < 4; ++m) {
            const int gm = tm * BM + wr * 64 + m * 16 + fq * 4;
#pragma unroll
            for (int r = 0; r < 4; ++r) {
                scores[(size_t)(gm + r) * Vv + gn] = fmaf(2.f, acc[m][n][r], -t);
            }
        }
    }
}

// ---------------------------------------------------------------------------
// Kernel 3: per-row finalize (unchanged from round 3 — passed)
// ---------------------------------------------------------------------------
__global__ __launch_bounds__(256) void finalize_kernel(const float* __restrict__ A,
                                                       const float* __restrict__ W,
                                                       float* __restrict__ out0,
                                                       float* __restrict__ out1,
                                                       float* __restrict__ out2,
                                                       float* __restrict__ out3,
                                                       float* __restrict__ out4) {
    const int row = blockIdx.x;
    const int tid = threadIdx.x;
    float* srow = out4 + (size_t)row * Vv;
    float* hrow = out3 + (size_t)row * Vv;
    constexpr int NV4 = Vv >> 2;

    const float4* s4 = reinterpret_cast<const float4*>(srow);

    float m = -INFINITY;
    int   idx = 0;
    float sum = 0.f;
    for (int i = tid; i < NV4; i += 256) {
        const float4 v = s4[i];
        const float vv[4] = {v.x, v.y, v.z, v.w};
#pragma unroll
        for (int j = 0; j < 4; ++j) {
            const float val = vv[j];
            if (val > m) {
                sum *= exp2f((m - val) * SC);
                m = val;
                idx = 4 * i + j;
            }
            sum += exp2f((val - m) * SC);
        }
    }
    if (tid == 0) {
        const float val = srow[Vv - 1];
        if (val > m) { sum *= exp2f((m - val) * SC); m = val; idx = Vv - 1; }
        sum += exp2f((val - m) * SC);
    }

    __shared__ float smax[256];
    __shared__ int   sidx[256];
    __shared__ float ssum[256];
    smax[tid] = m; sidx[tid] = idx; ssum[tid] = sum;
    __syncthreads();
#pragma unroll
    for (int off = 128; off > 0; off >>= 1) {
        if (tid < off) {
            const float m1 = smax[tid], m2 = smax[tid + off];
            const int   i1 = sidx[tid], i2 = sidx[tid + off];
            const float s1 = ssum[tid], s2 = ssum[tid + off];
            if (m2 > m1 || (m2 == m1 && i2 < i1)) {
                smax[tid] = m2; sidx[tid] = i2;
                ssum[tid] = s1 * exp2f((m1 - m2) * SC) + s2;
            } else {
                ssum[tid] = s1 + s2 * exp2f((m2 - m1) * SC);
            }
        }
        __syncthreads();
    }
    const float gmax = smax[0];
    const int   pred = sidx[0];
    const float inv  = 1.0f / ssum[0];
    __syncthreads();

    float4* p4 = reinterpret_cast<float4*>(srow);
    float4* h4 = reinterpret_cast<float4*>(hrow);
    for (int i = tid; i < NV4; i += 256) {
        const float4 v = s4[i];
        const int b = 4 * i;
        float4 p, h;
        p.x = exp2f((v.x - gmax) * SC) * inv;
        p.y = exp2f((v.y - gmax) * SC) * inv;
        p.z = exp2f((v.z - gmax) * SC) * inv;
        p.w = exp2f((v.w - gmax) * SC) * inv;
        h.x = (b + 0 == pred) ? 1.f : 0.f;
        h.y = (b + 1 == pred) ? 1.f : 0.f;
        h.z = (b + 2 == pred) ? 1.f : 0.f;
        h.w = (b + 3 == pred) ? 1.f : 0.f;
        p4[i] = p;
        h4[i] = h;
    }
    if (tid == 0) {
        const float val = srow[Vv - 1];
        srow[Vv - 1] = exp2f((val - gmax) * SC) * inv;
        hrow[Vv - 1] = (pred == Vv - 1) ? 1.f : 0.f;
        out2[row] = (float)pred;
    }

    const float4* wrow = reinterpret_cast<const float4*>(W + (size_t)pred * Dd);
    const float4* arow = reinterpret_cast<const float4*>(A + (size_t)row * Dd);
    float4* o0 = reinterpret_cast<float4*>(out0 + (size_t)row * Dd);
    float4* o1 = reinterpret_cast<float4*>(out1 + (size_t)row * Dd);
    if (tid < Dd / 4) {
        o0[tid] = wrow[tid];
        o1[tid] = arow[tid];
    }
}

}  // namespace

extern "C" void kernel_launch(void* const* d_in, const int* in_sizes, int n_in,
                              void* d_out, int out_size, void* d_ws, size_t ws_size,
                              hipStream_t stream) {
    const float* pred_embeds  = (const float*)d_in[0];   // (4,256,768)
    const float* embed_weight = (const float*)d_in[1];   // (50257,768)

    float* out  = (float*)d_out;
    float* out0 = out;                                    // (B,S,D)
    float* out1 = out0 + (size_t)Mm * Dd;                 // (B,S,D)
    float* out2 = out1 + (size_t)Mm * Dd;                 // (B,S)
    float* out3 = out2 + Mm;                              // (B,S,V) one-hot (scratch until finalize)
    float* out4 = out3 + (size_t)Mm * Vv;                 // (B,S,V) probs (scores until finalize)

    // packed scratch inside the out3 region (finalize overwrites it at the end)
    _Float16* Whp = (_Float16*)out3;
    _Float16* Wlp = Whp + WPLANE;
    _Float16* Ahp = Wlp + WPLANE;
    _Float16* Alp = Ahp + APLANE;
    float*    tsq = (float*)(Alp + APLANE);

    tsq_kernel<<<(Vv + 3) / 4, 256, 0, stream>>>(embed_weight, tsq);
    convert_pack<<<dim3(TW, 12), 256, 0, stream>>>(embed_weight, Whp, Wlp, Vv);
    convert_pack<<<dim3(TA, 12), 256, 0, stream>>>(pred_embeds, Ahp, Alp, Mm);

    gemm_kernel<<<dim3(TW, TA), 256, 0, stream>>>(Ahp, Alp, Whp, Wlp, tsq, out4);

    finalize_kernel<<<Mm, 256, 0, stream>>>(pred_embeds, embed_weight,
                                            out0, out1, out2, out3, out4);
}

// Round 5
// 519.005 us; speedup vs baseline: 1.0590x; 1.0590x over previous
//
#include <hip/hip_runtime.h>
#include <math.h>

namespace {

constexpr int Bb = 4, Ss = 256, Dd = 768, Vv = 50257;
constexpr int Mm = Bb * Ss;               // 1024 rows
constexpr int BM = 128, BN = 128, BK = 32;
constexpr int NS = Dd / BK;               // 24 k-steps
constexpr int TW = (Vv + BN - 1) / BN;    // 393 W tiles (last padded w/ zeros)
constexpr int TA = Mm / BM;               // 8 A tiles
constexpr int CHUNK = BM * BK;            // 4096 f16 = 8 KB per (tile, step) per plane
constexpr float SC = 14.4269504088896341f;   // 10 * log2(e)

typedef _Float16 f16x8 __attribute__((ext_vector_type(8)));
typedef float f32x4 __attribute__((ext_vector_type(4)));

// Packed scratch layout (inside out3 region, overwritten by finalize at the end):
//   Whp[TW*NS*CHUNK] , Wlp[...] , Ahp[TA*NS*CHUNK] , Alp[...] , tsq[Vv] , asq[Mm]
constexpr size_t WPLANE = (size_t)TW * NS * CHUNK;   // 38,633,472 f16
constexpr size_t APLANE = (size_t)TA * NS * CHUNK;   //    786,432 f16
// total bytes = 2*(WPLANE+APLANE)*2 + (Vv+Mm)*4 = 157,884,740 < out3 bytes (205,852,672)

__device__ __forceinline__ void gload_lds16(const void* g, void* l) {
    typedef __attribute__((address_space(3))) void lds_t;
    typedef const __attribute__((address_space(1))) void gm_t;
    __builtin_amdgcn_global_load_lds((gm_t*)g, (lds_t*)l, 16, 0, 0);
}

// ---------------------------------------------------------------------------
// Kernel 1: fused split-convert + pack + row-sumsq.
// grid (ntiles, 2), block 256. Thread: row = by*64 + (tid>>2), quarter q=tid&3
// handles steps s = q*6 .. q*6+5. Each step: read 32 floats (one 128B line),
// split to hi/lo f16, store packed; accumulate sum(x^2); 4-lane shfl reduce
// writes sumsq[row]. Rows >= nrows are packed as zeros.
// ---------------------------------------------------------------------------
__global__ __launch_bounds__(256) void convert_pack_tsq(const float* __restrict__ src,
                                                        _Float16* __restrict__ hp,
                                                        _Float16* __restrict__ lp,
                                                        float* __restrict__ sumsq,
                                                        int nrows) {
    const int t   = blockIdx.x;
    const int tid = threadIdx.x;
    const int r   = blockIdx.y * 64 + (tid >> 2);   // 0..127 tile row
    const int q   = tid & 3;                        // step quarter
    const int v   = t * BM + r;
    const bool valid = v < nrows;

    float sq = 0.f;
#pragma unroll
    for (int i = 0; i < 6; ++i) {
        const int s = q * 6 + i;
        float vals[32];
        if (valid) {
            const float4* p = reinterpret_cast<const float4*>(src + (size_t)v * Dd + s * BK);
#pragma unroll
            for (int k = 0; k < 8; ++k) *reinterpret_cast<float4*>(&vals[4 * k]) = p[k];
        } else {
#pragma unroll
            for (int k = 0; k < 32; ++k) vals[k] = 0.f;
        }
        const size_t chunk = ((size_t)t * NS + s) * CHUNK;
#pragma unroll
        for (int fq = 0; fq < 4; ++fq) {
            _Float16 hi[8], lo[8];
#pragma unroll
            for (int e = 0; e < 8; ++e) {
                const float x = vals[fq * 8 + e];
                sq = fmaf(x, x, sq);
                const _Float16 h = (_Float16)x;
                hi[e] = h;
                lo[e] = (_Float16)(x - (float)h);
            }
            *reinterpret_cast<f16x8*>(&hp[chunk + fq * (BM * 8) + (size_t)r * 8]) =
                *reinterpret_cast<const f16x8*>(hi);
            *reinterpret_cast<f16x8*>(&lp[chunk + fq * (BM * 8) + (size_t)r * 8]) =
                *reinterpret_cast<const f16x8*>(lo);
        }
    }
    sq += __shfl_xor(sq, 1);
    sq += __shfl_xor(sq, 2);
    if (valid && q == 0) sumsq[v] = sq;
}

// ---------------------------------------------------------------------------
// Kernel 2: scores = 2*(A.W^T) - tsq  via packed split-f16 MFMA, m97 structure.
// 1-D grid of 3200 with XCD-chunked remap: the 8 tm-blocks sharing a W tile
// run consecutively on the SAME XCD -> W tile stays L2-resident.
// ---------------------------------------------------------------------------
__global__ __launch_bounds__(256) void gemm_kernel(const _Float16* __restrict__ Ahp,
                                                   const _Float16* __restrict__ Alp,
                                                   const _Float16* __restrict__ Whp,
                                                   const _Float16* __restrict__ Wlp,
                                                   const float* __restrict__ tsq,
                                                   float* __restrict__ scores) {
    __shared__ _Float16 lds[4][CHUNK];     // 0:Ah 1:Al 2:Wh 3:Wl  (32 KB)

    const int b    = blockIdx.x;
    const int xcd  = b & 7;
    const int slot = b >> 3;
    const int tn   = xcd * 50 + (slot >> 3);   // contiguous tn chunk per XCD
    const int tm   = slot & 7;
    if (tn >= TW) return;

    const int tid  = threadIdx.x;
    const int wid  = tid >> 6;
    const int lane = tid & 63;
    const int wr   = wid >> 1;             // wave row (0..1)
    const int wc   = wid & 1;              // wave col (0..1)
    const int fr   = lane & 15;
    const int fq   = lane >> 4;

    const _Float16* gA_h = Ahp + (size_t)tm * NS * CHUNK;
    const _Float16* gA_l = Alp + (size_t)tm * NS * CHUNK;
    const _Float16* gW_h = Whp + (size_t)tn * NS * CHUNK;
    const _Float16* gW_l = Wlp + (size_t)tn * NS * CHUNK;

    f32x4 acc[4][4];
#pragma unroll
    for (int m = 0; m < 4; ++m)
#pragma unroll
        for (int n = 0; n < 4; ++n) acc[m][n] = (f32x4){0.f, 0.f, 0.f, 0.f};

    for (int s = 0; s < NS; ++s) {
        if (s) __syncthreads();
        const size_t so = (size_t)s * CHUNK;
        const _Float16* gsrc[4] = {gA_h + so, gA_l + so, gW_h + so, gW_l + so};
#pragma unroll
        for (int c = 0; c < 4; ++c) {
#pragma unroll
            for (int i = 0; i < 2; ++i) {
                const int seg = wid * 2 + i;              // 0..7, wave-uniform
                gload_lds16(gsrc[c] + seg * 512 + lane * 8, &lds[c][seg * 512]);
            }
        }
        __syncthreads();

        f16x8 ah[4], al[4];
#pragma unroll
        for (int m = 0; m < 4; ++m) {
            const int r = wr * 64 + m * 16 + fr;
            ah[m] = *reinterpret_cast<const f16x8*>(&lds[0][fq * (BM * 8) + r * 8]);
            al[m] = *reinterpret_cast<const f16x8*>(&lds[1][fq * (BM * 8) + r * 8]);
        }
#pragma unroll
        for (int n = 0; n < 4; ++n) {
            const int c = wc * 64 + n * 16 + fr;
            const f16x8 wh = *reinterpret_cast<const f16x8*>(&lds[2][fq * (BM * 8) + c * 8]);
            const f16x8 wl = *reinterpret_cast<const f16x8*>(&lds[3][fq * (BM * 8) + c * 8]);
#pragma unroll
            for (int m = 0; m < 4; ++m) {
                acc[m][n] = __builtin_amdgcn_mfma_f32_16x16x32_f16(ah[m], wh, acc[m][n], 0, 0, 0);
                acc[m][n] = __builtin_amdgcn_mfma_f32_16x16x32_f16(al[m], wh, acc[m][n], 0, 0, 0);
                acc[m][n] = __builtin_amdgcn_mfma_f32_16x16x32_f16(ah[m], wl, acc[m][n], 0, 0, 0);
            }
        }
    }

#pragma unroll
    for (int n = 0; n < 4; ++n) {
        const int gn = tn * BN + wc * 64 + n * 16 + fr;
        if (gn >= Vv) continue;
        const float t = tsq[gn];
#pragma unroll
        for (int m = 0; m < 4; ++m) {
            const int gm = tm * BM + wr * 64 + m * 16 + fq * 4;
#pragma unroll
            for (int r = 0; r < 4; ++r) {
                scores[(size_t)(gm + r) * Vv + gn] = fmaf(2.f, acc[m][n][r], -t);
            }
        }
    }
}

// ---------------------------------------------------------------------------
// Kernel 3: per-row finalize. Pass1: online max/argmax/exp-sum with FOUR
// independent accumulator streams (ILP); pass2: probs + one-hot, float4.
// ---------------------------------------------------------------------------
__global__ __launch_bounds__(256) void finalize_kernel(const float* __restrict__ A,
                                                       const float* __restrict__ W,
                                                       float* __restrict__ out0,
                                                       float* __restrict__ out1,
                                                       float* __restrict__ out2,
                                                       float* __restrict__ out3,
                                                       float* __restrict__ out4) {
    const int row = blockIdx.x;
    const int tid = threadIdx.x;
    float* srow = out4 + (size_t)row * Vv;
    float* hrow = out3 + (size_t)row * Vv;
    constexpr int NV4 = Vv >> 2;

    const float4* s4 = reinterpret_cast<const float4*>(srow);

    float m4[4]  = {-INFINITY, -INFINITY, -INFINITY, -INFINITY};
    int   id4[4] = {0, 0, 0, 0};
    float sm4[4] = {0.f, 0.f, 0.f, 0.f};
    for (int i = tid; i < NV4; i += 256) {
        const float4 v = s4[i];
        const float vv[4] = {v.x, v.y, v.z, v.w};
#pragma unroll
        for (int j = 0; j < 4; ++j) {
            const float val = vv[j];
            if (val > m4[j]) {
                sm4[j] *= exp2f((m4[j] - val) * SC);
                m4[j] = val;
                id4[j] = 4 * i + j;
            }
            sm4[j] += exp2f((val - m4[j]) * SC);
        }
    }
    float m = m4[0];
    int   idx = id4[0];
    float sum = sm4[0];
#pragma unroll
    for (int j = 1; j < 4; ++j) {
        if (m4[j] > m || (m4[j] == m && id4[j] < idx)) {
            sum = sum * exp2f((m - m4[j]) * SC) + sm4[j];
            m = m4[j];
            idx = id4[j];
        } else {
            sum += sm4[j] * exp2f((m4[j] - m) * SC);
        }
    }
    if (tid == 0) {
        const float val = srow[Vv - 1];
        if (val > m) { sum *= exp2f((m - val) * SC); m = val; idx = Vv - 1; }
        sum += exp2f((val - m) * SC);
    }

    __shared__ float smax[256];
    __shared__ int   sidx[256];
    __shared__ float ssum[256];
    smax[tid] = m; sidx[tid] = idx; ssum[tid] = sum;
    __syncthreads();
#pragma unroll
    for (int off = 128; off > 0; off >>= 1) {
        if (tid < off) {
            const float m1 = smax[tid], m2 = smax[tid + off];
            const int   i1 = sidx[tid], i2 = sidx[tid + off];
            const float s1 = ssum[tid], s2 = ssum[tid + off];
            if (m2 > m1 || (m2 == m1 && i2 < i1)) {
                smax[tid] = m2; sidx[tid] = i2;
                ssum[tid] = s1 * exp2f((m1 - m2) * SC) + s2;
            } else {
                ssum[tid] = s1 + s2 * exp2f((m2 - m1) * SC);
            }
        }
        __syncthreads();
    }
    const float gmax = smax[0];
    const int   pred = sidx[0];
    const float inv  = 1.0f / ssum[0];
    __syncthreads();

    float4* p4 = reinterpret_cast<float4*>(srow);
    float4* h4 = reinterpret_cast<float4*>(hrow);
    for (int i = tid; i < NV4; i += 256) {
        const float4 v = s4[i];
        const int b = 4 * i;
        float4 p, h;
        p.x = exp2f((v.x - gmax) * SC) * inv;
        p.y = exp2f((v.y - gmax) * SC) * inv;
        p.z = exp2f((v.z - gmax) * SC) * inv;
        p.w = exp2f((v.w - gmax) * SC) * inv;
        h.x = (b + 0 == pred) ? 1.f : 0.f;
        h.y = (b + 1 == pred) ? 1.f : 0.f;
        h.z = (b + 2 == pred) ? 1.f : 0.f;
        h.w = (b + 3 == pred) ? 1.f : 0.f;
        p4[i] = p;
        h4[i] = h;
    }
    if (tid == 0) {
        const float val = srow[Vv - 1];
        srow[Vv - 1] = exp2f((val - gmax) * SC) * inv;
        hrow[Vv - 1] = (pred == Vv - 1) ? 1.f : 0.f;
        out2[row] = (float)pred;
    }

    const float4* wrow = reinterpret_cast<const float4*>(W + (size_t)pred * Dd);
    const float4* arow = reinterpret_cast<const float4*>(A + (size_t)row * Dd);
    float4* o0 = reinterpret_cast<float4*>(out0 + (size_t)row * Dd);
    float4* o1 = reinterpret_cast<float4*>(out1 + (size_t)row * Dd);
    if (tid < Dd / 4) {
        o0[tid] = wrow[tid];
        o1[tid] = arow[tid];
    }
}

}  // namespace

extern "C" void kernel_launch(void* const* d_in, const int* in_sizes, int n_in,
                              void* d_out, int out_size, void* d_ws, size_t ws_size,
                              hipStream_t stream) {
    const float* pred_embeds  = (const float*)d_in[0];   // (4,256,768)
    const float* embed_weight = (const float*)d_in[1];   // (50257,768)

    float* out  = (float*)d_out;
    float* out0 = out;                                    // (B,S,D)
    float* out1 = out0 + (size_t)Mm * Dd;                 // (B,S,D)
    float* out2 = out1 + (size_t)Mm * Dd;                 // (B,S)
    float* out3 = out2 + Mm;                              // (B,S,V) one-hot (scratch until finalize)
    float* out4 = out3 + (size_t)Mm * Vv;                 // (B,S,V) probs (scores until finalize)

    // packed scratch inside the out3 region (finalize overwrites it at the end)
    _Float16* Whp = (_Float16*)out3;
    _Float16* Wlp = Whp + WPLANE;
    _Float16* Ahp = Wlp + WPLANE;
    _Float16* Alp = Ahp + APLANE;
    float*    tsq = (float*)(Alp + APLANE);
    float*    asq = tsq + Vv;     // A row-sumsq (computed, unused)

    convert_pack_tsq<<<dim3(TW, 2), 256, 0, stream>>>(embed_weight, Whp, Wlp, tsq, Vv);
    convert_pack_tsq<<<dim3(TA, 2), 256, 0, stream>>>(pred_embeds, Ahp, Alp, asq, Mm);

    gemm_kernel<<<3200, 256, 0, stream>>>(Ahp, Alp, Whp, Wlp, tsq, out4);

    finalize_kernel<<<Mm, 256, 0, stream>>>(pred_embeds, embed_weight,
                                            out0, out1, out2, out3, out4);
}